// Round 3
// baseline (776.994 us; speedup 1.0000x reference)
//
#include <hip/hip_runtime.h>
#include <hip/hip_bf16.h>

#define B_SZ 32
#define N_SZ 2048
#define H_SZ 1024

typedef float f32x4 __attribute__((ext_vector_type(4)));
typedef short bf16x8 __attribute__((ext_vector_type(8)));

static __device__ __forceinline__ unsigned short f2bf(float f) {
    union { float f; unsigned u; } x; x.f = f;
    unsigned r = x.u + 0x7FFF + ((x.u >> 16) & 1);
    return (unsigned short)(r >> 16);
}

// fast tanh: (e^{2x}-1)/(e^{2x}+1), clamped so e never overflows
static __device__ __forceinline__ float fast_tanh(float x) {
    x = fminf(fmaxf(x, -15.f), 15.f);
    float e = __expf(2.f * x);
    return (e - 1.f) / (e + 1.f);
}

// ---------------- kernel 1: pack Wv f32 -> bf16 in wave-fragment order ----------------
// packed element index: ((((w*32 + k)*4 + t)*64) + lane)*8 + j
//   maps to Wv[g][h], g = w*64 + 16t + (lane&15), h = k*32 + (lane>>4)*8 + j
__global__ __launch_bounds__(256) void pack_wv_kernel(const float* __restrict__ wv,
                                                      short* __restrict__ out) {
    int o8 = blockIdx.x * 256 + threadIdx.x;      // 131072 threads, 8 elems each
    int lane = o8 & 63;
    int t    = (o8 >> 6) & 3;
    int k    = (o8 >> 8) & 31;
    int w    = (o8 >> 13) & 15;
    int g  = w * 64 + 16 * t + (lane & 15);
    int h0 = k * 32 + (lane >> 4) * 8;
    const float* src = wv + (size_t)g * 1024 + h0;
    float4 v0 = *(const float4*)(src);
    float4 v1 = *(const float4*)(src + 4);
    short4 s0, s1;
    s0.x = (short)f2bf(v0.x); s0.y = (short)f2bf(v0.y);
    s0.z = (short)f2bf(v0.z); s0.w = (short)f2bf(v0.w);
    s1.x = (short)f2bf(v1.x); s1.y = (short)f2bf(v1.y);
    s1.z = (short)f2bf(v1.z); s1.w = (short)f2bf(v1.w);
    *(short4*)(out + (size_t)o8 * 8)     = s0;
    *(short4*)(out + (size_t)o8 * 8 + 4) = s1;
}

// ---------------- kernel 2: q_hid = query @ Wq.T + bias ----------------
__global__ __launch_bounds__(256) void qhid_kernel(const float* __restrict__ query,
                                                   const float* __restrict__ Wq,
                                                   const float* __restrict__ bias,
                                                   float* __restrict__ qh) {
    int gb = blockIdx.x * 4;
    __shared__ float wsm[4][1024];
    int t = threadIdx.x;
    for (int i = t; i < 4096; i += 256)
        wsm[i >> 10][i & 1023] = Wq[(size_t)gb * 1024 + i];
    __syncthreads();
    int gi = t >> 6;
    int lane = t & 63;
    int b = lane >> 1;
    int half = lane & 1;
    const float4* q = (const float4*)(query + b * 1024 + half * 512);
    const float4* w = (const float4*)(&wsm[gi][half * 512]);
    float acc = 0.f;
#pragma unroll 8
    for (int h = 0; h < 128; ++h) {
        float4 qv = q[h]; float4 wv = w[h];
        acc += qv.x * wv.x + qv.y * wv.y + qv.z * wv.z + qv.w * wv.w;
    }
    acc += __shfl_xor(acc, 1);
    if (half == 0) qh[b * 1024 + gb + gi] = acc + bias[gb + gi];
}

// ---------------- kernel 3: fused score GEMM + tanh + Wm dot ----------------
// 512 threads (8 waves); one 64-row panel per block; full K=1024 in LDS.
// B from packed layout: per (wslot,k,t) one contiguous 1KB wave load.
__global__ __launch_bounds__(512) void fused_score_kernel(
    const float* __restrict__ value, const float* __restrict__ cov,
    const short* __restrict__ wv_pk, const float* __restrict__ qh,
    const float* __restrict__ Wc, const float* __restrict__ Wm,
    float* __restrict__ e_out)
{
    extern __shared__ char smem[];
    float* e_sm = (float*)(smem + 64 * 1024 * 2);

    const int p   = blockIdx.x;
    const int b   = p >> 5;
    const int n0  = (p & 31) * 64;
    const int tid = threadIdx.x;

    if (tid < 64) e_sm[tid] = 0.f;

    // ---- stage value[b, n0..n0+64, :] as bf16 into swizzled LDS ----
    const float* src = value + ((size_t)(b * N_SZ + n0)) * H_SZ;
#pragma unroll 4
    for (int it = 0; it < 32; ++it) {
        int idx = (it * 512 + tid) * 4;
        float4 v = *(const float4*)(src + idx);
        int row = idx >> 10;
        int col = idx & 1023;
        unsigned byteoff = (unsigned)(row * 2048 + col * 2) ^ (unsigned)((row & 7) << 4);
        short4 s;
        s.x = (short)f2bf(v.x); s.y = (short)f2bf(v.y);
        s.z = (short)f2bf(v.z); s.w = (short)f2bf(v.w);
        *(short4*)(smem + byteoff) = s;
    }
    __syncthreads();

    const int wave = tid >> 6;
    const int lane = tid & 63;
    const int lrow = lane & 15;
    const int lgrp = lane >> 4;
    const unsigned xorm = (unsigned)((lrow & 7) << 4);
    // carry-safe swizzled bases: all k/r offsets fold to +immediate
    const unsigned base_e = ((unsigned)(lrow * 2048 + lgrp * 16)) ^ xorm;
    const unsigned base_o = ((unsigned)(lrow * 2048 + 64 + lgrp * 16)) ^ xorm;

    float cv[4][4];
#pragma unroll
    for (int r = 0; r < 4; ++r)
#pragma unroll
        for (int i = 0; i < 4; ++i)
            cv[r][i] = cov[b * N_SZ + n0 + 16 * r + lgrp * 4 + i];

    float s_part[4][4];
#pragma unroll
    for (int r = 0; r < 4; ++r)
#pragma unroll
        for (int i = 0; i < 4; ++i) s_part[r][i] = 0.f;

#pragma unroll 1
    for (int j = 0; j < 2; ++j) {
        const int gbase = wave * 128 + j * 64;
        const int wslot = wave * 2 + j;              // 64-g block index, 0..15
        // lane's byte base within the packed B stream for this g-block
        const short* bbase = wv_pk + (size_t)wslot * 65536 + lane * 8;

        f32x4 acc[4][4];
#pragma unroll
        for (int r = 0; r < 4; ++r)
#pragma unroll
            for (int t = 0; t < 4; ++t) acc[r][t] = (f32x4){0.f, 0.f, 0.f, 0.f};

        // depth-3 register prefetch pipeline for B fragments
        bf16x8 bA[4], bB[4], bC[4];
#pragma unroll
        for (int t = 0; t < 4; ++t) {
            bA[t] = *(const bf16x8*)(bbase + 0 * 2048 + t * 512);
            bB[t] = *(const bf16x8*)(bbase + 1 * 2048 + t * 512);
            bC[t] = *(const bf16x8*)(bbase + 2 * 2048 + t * 512);
        }

#pragma unroll
        for (int k = 0; k < 32; ++k) {
            bf16x8 afr[4];
#pragma unroll
            for (int r = 0; r < 4; ++r) {
                unsigned off = ((k & 1) ? base_o : base_e) + (unsigned)(r * 32768 + (k >> 1) * 128);
                afr[r] = *(const bf16x8*)(smem + off);
            }
#pragma unroll
            for (int r = 0; r < 4; ++r)
#pragma unroll
                for (int t = 0; t < 4; ++t)
                    acc[r][t] = __builtin_amdgcn_mfma_f32_16x16x32_bf16(
                        afr[r], bA[t], acc[r][t], 0, 0, 0);
            // rotate and prefetch k+3 (renamed away by full unroll)
#pragma unroll
            for (int t = 0; t < 4; ++t) { bA[t] = bB[t]; bB[t] = bC[t]; }
            if (k + 3 < 32) {
#pragma unroll
                for (int t = 0; t < 4; ++t)
                    bC[t] = *(const bf16x8*)(bbase + (k + 3) * 2048 + t * 512);
            }
        }

        // epilogue: a = acc + qh + cov*Wc ; e_part += tanh(a)*Wm
#pragma unroll
        for (int t = 0; t < 4; ++t) {
            int g = gbase + 16 * t + lrow;
            float qv = qh[b * 1024 + g];
            float wc = Wc[g];
            float wm = Wm[g];
#pragma unroll
            for (int r = 0; r < 4; ++r)
#pragma unroll
                for (int i = 0; i < 4; ++i) {
                    float aval = acc[r][t][i] + qv + cv[r][i] * wc;
                    s_part[r][i] += fast_tanh(aval) * wm;
                }
        }
    }

    // reduce across the 16 lanes sharing a row, then accumulate into LDS
#pragma unroll
    for (int r = 0; r < 4; ++r)
#pragma unroll
        for (int i = 0; i < 4; ++i) {
            float s = s_part[r][i];
            s += __shfl_xor(s, 1);
            s += __shfl_xor(s, 2);
            s += __shfl_xor(s, 4);
            s += __shfl_xor(s, 8);
            if (lrow == 0) atomicAdd(&e_sm[16 * r + lgrp * 4 + i], s);
        }
    __syncthreads();
    if (tid < 64) e_out[b * N_SZ + n0 + tid] = e_sm[tid];
}

// ---------------- kernel 4: mask + softmax over n ----------------
__global__ __launch_bounds__(256) void softmax_kernel(const float* __restrict__ e,
                                                      const int* __restrict__ mask,
                                                      const float* __restrict__ bm,
                                                      float* __restrict__ attn_out) {
    int b = blockIdx.x;
    int t = threadIdx.x;
    int wave = t >> 6, lane = t & 63;
    float bmv = bm[0];
    float vals[8];
    float mx = -1e30f;
#pragma unroll
    for (int j = 0; j < 8; ++j) {
        int n = t + 256 * j;
        float ev = e[b * N_SZ + n] + bmv;
        if (mask[b * N_SZ + n] <= 0) ev = -1e9f;
        vals[j] = ev;
        mx = fmaxf(mx, ev);
    }
#pragma unroll
    for (int m = 1; m < 64; m <<= 1) mx = fmaxf(mx, __shfl_xor(mx, m));
    __shared__ float redmax[4], redsum[4];
    if (lane == 0) redmax[wave] = mx;
    __syncthreads();
    mx = fmaxf(fmaxf(redmax[0], redmax[1]), fmaxf(redmax[2], redmax[3]));
    float sum = 0.f;
#pragma unroll
    for (int j = 0; j < 8; ++j) {
        vals[j] = expf(vals[j] - mx);
        sum += vals[j];
    }
#pragma unroll
    for (int m = 1; m < 64; m <<= 1) sum += __shfl_xor(sum, m);
    if (lane == 0) redsum[wave] = sum;
    __syncthreads();
    sum = redsum[0] + redsum[1] + redsum[2] + redsum[3];
    float inv = 1.f / sum;
#pragma unroll
    for (int j = 0; j < 8; ++j)
        attn_out[b * N_SZ + t + 256 * j] = vals[j] * inv;
}

// ---------------- kernel 5: partial weighted value sum (16 chunks/batch) ----------------
__global__ __launch_bounds__(256) void wsum_partial_kernel(const float* __restrict__ attn,
                                                           const float* __restrict__ value,
                                                           float* __restrict__ partial) {
    int b = blockIdx.x >> 4;
    int c = blockIdx.x & 15;
    int t = threadIdx.x;
    float4 acc = {0.f, 0.f, 0.f, 0.f};
    const float* vbase = value + (size_t)(b * N_SZ + c * 128) * H_SZ;
    const float* abase = attn + b * N_SZ + c * 128;
    for (int n = 0; n < 128; ++n) {
        float a = abase[n];
        if (a != 0.f) {
            float4 v = *(const float4*)(vbase + (size_t)n * H_SZ + t * 4);
            acc.x += a * v.x; acc.y += a * v.y;
            acc.z += a * v.z; acc.w += a * v.w;
        }
    }
    *(float4*)(partial + (size_t)blockIdx.x * H_SZ + t * 4) = acc;
}

// ---------------- kernel 6: reduce partials -> output ----------------
__global__ __launch_bounds__(256) void wsum_reduce_kernel(const float* __restrict__ partial,
                                                          float* __restrict__ out) {
    int i = blockIdx.x * 256 + threadIdx.x;   // 32768 total
    int b = i >> 10;
    int h = i & 1023;
    float s = 0.f;
#pragma unroll
    for (int c = 0; c < 16; ++c) s += partial[(size_t)(b * 16 + c) * H_SZ + h];
    out[i] = s;
}

extern "C" void kernel_launch(void* const* d_in, const int* in_sizes, int n_in,
                              void* d_out, int out_size, void* d_ws, size_t ws_size,
                              hipStream_t stream) {
    const float* query = (const float*)d_in[0];
    const float* value = (const float*)d_in[1];
    const int*   mask  = (const int*)  d_in[2];
    const float* cov   = (const float*)d_in[3];
    const float* Wq    = (const float*)d_in[4];
    const float* Wv    = (const float*)d_in[5];
    const float* Wc    = (const float*)d_in[6];
    const float* bias  = (const float*)d_in[7];
    const float* Wm    = (const float*)d_in[8];
    const float* bm    = (const float*)d_in[9];

    float* out      = (float*)d_out;            // [32*1024] output
    float* attn_out = out + B_SZ * H_SZ;        // [32*2048] attn

    char* ws = (char*)d_ws;
    short* wv_pk   = (short*)ws;                                       // 2 MB
    float* qh      = (float*)(ws + 2 * 1024 * 1024);                   // 128 KB
    float* e_buf   = (float*)(ws + 2 * 1024 * 1024 + 128 * 1024);      // 256 KB
    float* partial = (float*)(ws + 2 * 1024 * 1024 + 384 * 1024);      // 2 MB

    pack_wv_kernel<<<512, 256, 0, stream>>>(Wv, wv_pk);
    qhid_kernel<<<256, 256, 0, stream>>>(query, Wq, bias, qh);

    size_t smem = 64 * 1024 * 2 + 64 * 4;
    fused_score_kernel<<<1024, 512, smem, stream>>>(value, cov, wv_pk, qh, Wc, Wm, e_buf);

    softmax_kernel<<<B_SZ, 256, 0, stream>>>(e_buf, mask, bm, attn_out);
    wsum_partial_kernel<<<B_SZ * 16, 256, 0, stream>>>(attn_out, value, partial);
    wsum_reduce_kernel<<<128, 256, 0, stream>>>(partial, out);
}

// Round 4
// 242.914 us; speedup vs baseline: 3.1986x; 3.1986x over previous
//
#include <hip/hip_runtime.h>
#include <hip/hip_bf16.h>

#define B_SZ 32
#define N_SZ 2048
#define H_SZ 1024

typedef float f32x4 __attribute__((ext_vector_type(4)));
typedef short bf16x8 __attribute__((ext_vector_type(8)));

static __device__ __forceinline__ unsigned short f2bf(float f) {
    union { float f; unsigned u; } x; x.f = f;
    unsigned r = x.u + 0x7FFF + ((x.u >> 16) & 1);
    return (unsigned short)(r >> 16);
}

// fast tanh: (e^{2x}-1)/(e^{2x}+1), clamped so e never overflows
static __device__ __forceinline__ float fast_tanh(float x) {
    x = fminf(fmaxf(x, -15.f), 15.f);
    float e = __expf(2.f * x);
    return (e - 1.f) / (e + 1.f);
}

// ---------------- kernel 1: pack Wv f32 -> bf16 in wave-fragment order ----------------
// packed element index: ((((w*32 + k)*4 + t)*64) + lane)*8 + j
//   maps to Wv[g][h], g = w*64 + 16t + (lane&15), h = k*32 + (lane>>4)*8 + j
__global__ __launch_bounds__(256) void pack_wv_kernel(const float* __restrict__ wv,
                                                      short* __restrict__ out) {
    int o8 = blockIdx.x * 256 + threadIdx.x;      // 131072 threads, 8 elems each
    int lane = o8 & 63;
    int t    = (o8 >> 6) & 3;
    int k    = (o8 >> 8) & 31;
    int w    = (o8 >> 13) & 15;
    int g  = w * 64 + 16 * t + (lane & 15);
    int h0 = k * 32 + (lane >> 4) * 8;
    const float* src = wv + (size_t)g * 1024 + h0;
    float4 v0 = *(const float4*)(src);
    float4 v1 = *(const float4*)(src + 4);
    short4 s0, s1;
    s0.x = (short)f2bf(v0.x); s0.y = (short)f2bf(v0.y);
    s0.z = (short)f2bf(v0.z); s0.w = (short)f2bf(v0.w);
    s1.x = (short)f2bf(v1.x); s1.y = (short)f2bf(v1.y);
    s1.z = (short)f2bf(v1.z); s1.w = (short)f2bf(v1.w);
    *(short4*)(out + (size_t)o8 * 8)     = s0;
    *(short4*)(out + (size_t)o8 * 8 + 4) = s1;
}

// ---------------- kernel 2: q_hid = query @ Wq.T + bias ----------------
__global__ __launch_bounds__(256) void qhid_kernel(const float* __restrict__ query,
                                                   const float* __restrict__ Wq,
                                                   const float* __restrict__ bias,
                                                   float* __restrict__ qh) {
    int gb = blockIdx.x * 4;
    __shared__ float wsm[4][1024];
    int t = threadIdx.x;
    for (int i = t; i < 4096; i += 256)
        wsm[i >> 10][i & 1023] = Wq[(size_t)gb * 1024 + i];
    __syncthreads();
    int gi = t >> 6;
    int lane = t & 63;
    int b = lane >> 1;
    int half = lane & 1;
    const float4* q = (const float4*)(query + b * 1024 + half * 512);
    const float4* w = (const float4*)(&wsm[gi][half * 512]);
    float acc = 0.f;
#pragma unroll 8
    for (int h = 0; h < 128; ++h) {
        float4 qv = q[h]; float4 wv = w[h];
        acc += qv.x * wv.x + qv.y * wv.y + qv.z * wv.z + qv.w * wv.w;
    }
    acc += __shfl_xor(acc, 1);
    if (half == 0) qh[b * 1024 + gb + gi] = acc + bias[gb + gi];
}

// ---------------- kernel 3: fused score GEMM + tanh + Wm dot ----------------
// 512 threads (8 waves); one 64-row panel per block; full K=1024 in LDS.
// B from packed layout: per (wslot,k,t) one contiguous 1KB coalesced wave load.
// Depth-1 ping/pong B prefetch, unroll 2 (round-2 register budget: no spills).
__global__ __launch_bounds__(512, 2) void fused_score_kernel(
    const float* __restrict__ value, const float* __restrict__ cov,
    const short* __restrict__ wv_pk, const float* __restrict__ qh,
    const float* __restrict__ Wc, const float* __restrict__ Wm,
    float* __restrict__ e_out)
{
    extern __shared__ char smem[];
    float* e_sm = (float*)(smem + 64 * 1024 * 2);

    const int p   = blockIdx.x;
    const int b   = p >> 5;
    const int n0  = (p & 31) * 64;
    const int tid = threadIdx.x;

    if (tid < 64) e_sm[tid] = 0.f;

    // ---- stage value[b, n0..n0+64, :] as bf16 into swizzled LDS ----
    const float* src = value + ((size_t)(b * N_SZ + n0)) * H_SZ;
#pragma unroll 4
    for (int it = 0; it < 32; ++it) {
        int idx = (it * 512 + tid) * 4;
        float4 v = *(const float4*)(src + idx);
        int row = idx >> 10;
        int col = idx & 1023;
        unsigned byteoff = (unsigned)(row * 2048 + col * 2) ^ (unsigned)((row & 7) << 4);
        short4 s;
        s.x = (short)f2bf(v.x); s.y = (short)f2bf(v.y);
        s.z = (short)f2bf(v.z); s.w = (short)f2bf(v.w);
        *(short4*)(smem + byteoff) = s;
    }
    __syncthreads();

    const int wave = tid >> 6;
    const int lane = tid & 63;
    const int lrow = lane & 15;
    const int lgrp = lane >> 4;
    const unsigned xorm = (unsigned)((lrow & 7) << 4);
    // carry-safe swizzled bases: all k/r offsets fold to +immediate
    const unsigned base_e = ((unsigned)(lrow * 2048 + lgrp * 16)) ^ xorm;
    const unsigned base_o = ((unsigned)(lrow * 2048 + 64 + lgrp * 16)) ^ xorm;

    float cv[4][4];
#pragma unroll
    for (int r = 0; r < 4; ++r)
#pragma unroll
        for (int i = 0; i < 4; ++i)
            cv[r][i] = cov[b * N_SZ + n0 + 16 * r + lgrp * 4 + i];

    float s_part[4][4];
#pragma unroll
    for (int r = 0; r < 4; ++r)
#pragma unroll
        for (int i = 0; i < 4; ++i) s_part[r][i] = 0.f;

#pragma unroll 1
    for (int j = 0; j < 2; ++j) {
        const int gbase = wave * 128 + j * 64;
        const int wslot = wave * 2 + j;              // 64-g block index, 0..15
        // lane's base within the packed B stream for this g-block
        const short* bbase = wv_pk + (size_t)wslot * 65536 + lane * 8;

        f32x4 acc[4][4];
#pragma unroll
        for (int r = 0; r < 4; ++r)
#pragma unroll
            for (int t = 0; t < 4; ++t) acc[r][t] = (f32x4){0.f, 0.f, 0.f, 0.f};

        // depth-1 ping/pong prefetch for B fragments (coalesced 1KB loads)
        bf16x8 bc[4];
#pragma unroll
        for (int t = 0; t < 4; ++t)
            bc[t] = *(const bf16x8*)(bbase + t * 512);

#pragma unroll 2
        for (int k = 0; k < 32; ++k) {
            // issue next-k B loads first (wrap at end: harmless re-load of k=0)
            bf16x8 bn[4];
            int kn = (k + 1) & 31;
#pragma unroll
            for (int t = 0; t < 4; ++t)
                bn[t] = *(const bf16x8*)(bbase + kn * 2048 + t * 512);

            bf16x8 afr[4];
#pragma unroll
            for (int r = 0; r < 4; ++r) {
                unsigned off = ((k & 1) ? base_o : base_e) + (unsigned)(r * 32768 + (k >> 1) * 128);
                afr[r] = *(const bf16x8*)(smem + off);
            }
#pragma unroll
            for (int r = 0; r < 4; ++r)
#pragma unroll
                for (int t = 0; t < 4; ++t)
                    acc[r][t] = __builtin_amdgcn_mfma_f32_16x16x32_bf16(
                        afr[r], bc[t], acc[r][t], 0, 0, 0);
#pragma unroll
            for (int t = 0; t < 4; ++t) bc[t] = bn[t];
        }

        // epilogue: a = acc + qh + cov*Wc ; e_part += tanh(a)*Wm
#pragma unroll
        for (int t = 0; t < 4; ++t) {
            int g = gbase + 16 * t + lrow;
            float qv = qh[b * 1024 + g];
            float wc = Wc[g];
            float wm = Wm[g];
#pragma unroll
            for (int r = 0; r < 4; ++r)
#pragma unroll
                for (int i = 0; i < 4; ++i) {
                    float aval = acc[r][t][i] + qv + cv[r][i] * wc;
                    s_part[r][i] += fast_tanh(aval) * wm;
                }
        }
    }

    // reduce across the 16 lanes sharing a row, then accumulate into LDS
#pragma unroll
    for (int r = 0; r < 4; ++r)
#pragma unroll
        for (int i = 0; i < 4; ++i) {
            float s = s_part[r][i];
            s += __shfl_xor(s, 1);
            s += __shfl_xor(s, 2);
            s += __shfl_xor(s, 4);
            s += __shfl_xor(s, 8);
            if (lrow == 0) atomicAdd(&e_sm[16 * r + lgrp * 4 + i], s);
        }
    __syncthreads();
    if (tid < 64) e_out[b * N_SZ + n0 + tid] = e_sm[tid];
}

// ---------------- kernel 4: mask + softmax over n ----------------
__global__ __launch_bounds__(256) void softmax_kernel(const float* __restrict__ e,
                                                      const int* __restrict__ mask,
                                                      const float* __restrict__ bm,
                                                      float* __restrict__ attn_out) {
    int b = blockIdx.x;
    int t = threadIdx.x;
    int wave = t >> 6, lane = t & 63;
    float bmv = bm[0];
    float vals[8];
    float mx = -1e30f;
#pragma unroll
    for (int j = 0; j < 8; ++j) {
        int n = t + 256 * j;
        float ev = e[b * N_SZ + n] + bmv;
        if (mask[b * N_SZ + n] <= 0) ev = -1e9f;
        vals[j] = ev;
        mx = fmaxf(mx, ev);
    }
#pragma unroll
    for (int m = 1; m < 64; m <<= 1) mx = fmaxf(mx, __shfl_xor(mx, m));
    __shared__ float redmax[4], redsum[4];
    if (lane == 0) redmax[wave] = mx;
    __syncthreads();
    mx = fmaxf(fmaxf(redmax[0], redmax[1]), fmaxf(redmax[2], redmax[3]));
    float sum = 0.f;
#pragma unroll
    for (int j = 0; j < 8; ++j) {
        vals[j] = expf(vals[j] - mx);
        sum += vals[j];
    }
#pragma unroll
    for (int m = 1; m < 64; m <<= 1) sum += __shfl_xor(sum, m);
    if (lane == 0) redsum[wave] = sum;
    __syncthreads();
    sum = redsum[0] + redsum[1] + redsum[2] + redsum[3];
    float inv = 1.f / sum;
#pragma unroll
    for (int j = 0; j < 8; ++j)
        attn_out[b * N_SZ + t + 256 * j] = vals[j] * inv;
}

// ---------------- kernel 5: partial weighted value sum (16 chunks/batch) ----------------
__global__ __launch_bounds__(256) void wsum_partial_kernel(const float* __restrict__ attn,
                                                           const float* __restrict__ value,
                                                           float* __restrict__ partial) {
    int b = blockIdx.x >> 4;
    int c = blockIdx.x & 15;
    int t = threadIdx.x;
    float4 acc = {0.f, 0.f, 0.f, 0.f};
    const float* vbase = value + (size_t)(b * N_SZ + c * 128) * H_SZ;
    const float* abase = attn + b * N_SZ + c * 128;
    for (int n = 0; n < 128; ++n) {
        float a = abase[n];
        if (a != 0.f) {
            float4 v = *(const float4*)(vbase + (size_t)n * H_SZ + t * 4);
            acc.x += a * v.x; acc.y += a * v.y;
            acc.z += a * v.z; acc.w += a * v.w;
        }
    }
    *(float4*)(partial + (size_t)blockIdx.x * H_SZ + t * 4) = acc;
}

// ---------------- kernel 6: reduce partials -> output ----------------
__global__ __launch_bounds__(256) void wsum_reduce_kernel(const float* __restrict__ partial,
                                                          float* __restrict__ out) {
    int i = blockIdx.x * 256 + threadIdx.x;   // 32768 total
    int b = i >> 10;
    int h = i & 1023;
    float s = 0.f;
#pragma unroll
    for (int c = 0; c < 16; ++c) s += partial[(size_t)(b * 16 + c) * H_SZ + h];
    out[i] = s;
}

extern "C" void kernel_launch(void* const* d_in, const int* in_sizes, int n_in,
                              void* d_out, int out_size, void* d_ws, size_t ws_size,
                              hipStream_t stream) {
    const float* query = (const float*)d_in[0];
    const float* value = (const float*)d_in[1];
    const int*   mask  = (const int*)  d_in[2];
    const float* cov   = (const float*)d_in[3];
    const float* Wq    = (const float*)d_in[4];
    const float* Wv    = (const float*)d_in[5];
    const float* Wc    = (const float*)d_in[6];
    const float* bias  = (const float*)d_in[7];
    const float* Wm    = (const float*)d_in[8];
    const float* bm    = (const float*)d_in[9];

    float* out      = (float*)d_out;            // [32*1024] output
    float* attn_out = out + B_SZ * H_SZ;        // [32*2048] attn

    char* ws = (char*)d_ws;
    short* wv_pk   = (short*)ws;                                       // 2 MB
    float* qh      = (float*)(ws + 2 * 1024 * 1024);                   // 128 KB
    float* e_buf   = (float*)(ws + 2 * 1024 * 1024 + 128 * 1024);      // 256 KB
    float* partial = (float*)(ws + 2 * 1024 * 1024 + 384 * 1024);      // 2 MB

    pack_wv_kernel<<<512, 256, 0, stream>>>(Wv, wv_pk);
    qhid_kernel<<<256, 256, 0, stream>>>(query, Wq, bias, qh);

    size_t smem = 64 * 1024 * 2 + 64 * 4;
    fused_score_kernel<<<1024, 512, smem, stream>>>(value, cov, wv_pk, qh, Wc, Wm, e_buf);

    softmax_kernel<<<B_SZ, 256, 0, stream>>>(e_buf, mask, bm, attn_out);
    wsum_partial_kernel<<<B_SZ * 16, 256, 0, stream>>>(attn_out, value, partial);
    wsum_reduce_kernel<<<128, 256, 0, stream>>>(partial, out);
}

// Round 5
// 242.549 us; speedup vs baseline: 3.2035x; 1.0015x over previous
//
#include <hip/hip_runtime.h>
#include <hip/hip_bf16.h>

#define B_SZ 32
#define N_SZ 2048
#define H_SZ 1024

typedef float f32x4 __attribute__((ext_vector_type(4)));
typedef short bf16x8 __attribute__((ext_vector_type(8)));

static __device__ __forceinline__ unsigned short f2bf(float f) {
    union { float f; unsigned u; } x; x.f = f;
    unsigned r = x.u + 0x7FFF + ((x.u >> 16) & 1);
    return (unsigned short)(r >> 16);
}

// fast tanh: (e^{2x}-1)/(e^{2x}+1), clamped so e never overflows
static __device__ __forceinline__ float fast_tanh(float x) {
    x = fminf(fmaxf(x, -15.f), 15.f);
    float e = __expf(2.f * x);
    return (e - 1.f) / (e + 1.f);
}

// ---------------- kernel 1: pack Wv f32 -> bf16 in wave-fragment order ----------------
// packed element index: ((((w*32 + k)*4 + t)*64) + lane)*8 + j
//   maps to Wv[g][h], g = w*64 + 16t + (lane&15), h = k*32 + (lane>>4)*8 + j
__global__ __launch_bounds__(256) void pack_wv_kernel(const float* __restrict__ wv,
                                                      short* __restrict__ out) {
    int o8 = blockIdx.x * 256 + threadIdx.x;      // 131072 threads, 8 elems each
    int lane = o8 & 63;
    int t    = (o8 >> 6) & 3;
    int k    = (o8 >> 8) & 31;
    int w    = (o8 >> 13) & 15;
    int g  = w * 64 + 16 * t + (lane & 15);
    int h0 = k * 32 + (lane >> 4) * 8;
    const float* src = wv + (size_t)g * 1024 + h0;
    float4 v0 = *(const float4*)(src);
    float4 v1 = *(const float4*)(src + 4);
    short4 s0, s1;
    s0.x = (short)f2bf(v0.x); s0.y = (short)f2bf(v0.y);
    s0.z = (short)f2bf(v0.z); s0.w = (short)f2bf(v0.w);
    s1.x = (short)f2bf(v1.x); s1.y = (short)f2bf(v1.y);
    s1.z = (short)f2bf(v1.z); s1.w = (short)f2bf(v1.w);
    *(short4*)(out + (size_t)o8 * 8)     = s0;
    *(short4*)(out + (size_t)o8 * 8 + 4) = s1;
}

// ---------------- kernel 2: q_hid = query @ Wq.T + bias ----------------
__global__ __launch_bounds__(256) void qhid_kernel(const float* __restrict__ query,
                                                   const float* __restrict__ Wq,
                                                   const float* __restrict__ bias,
                                                   float* __restrict__ qh) {
    int gb = blockIdx.x * 4;
    __shared__ float wsm[4][1024];
    int t = threadIdx.x;
    for (int i = t; i < 4096; i += 256)
        wsm[i >> 10][i & 1023] = Wq[(size_t)gb * 1024 + i];
    __syncthreads();
    int gi = t >> 6;
    int lane = t & 63;
    int b = lane >> 1;
    int half = lane & 1;
    const float4* q = (const float4*)(query + b * 1024 + half * 512);
    const float4* w = (const float4*)(&wsm[gi][half * 512]);
    float acc = 0.f;
#pragma unroll 8
    for (int h = 0; h < 128; ++h) {
        float4 qv = q[h]; float4 wv = w[h];
        acc += qv.x * wv.x + qv.y * wv.y + qv.z * wv.z + qv.w * wv.w;
    }
    acc += __shfl_xor(acc, 1);
    if (half == 0) qh[b * 1024 + gb + gi] = acc + bias[gb + gi];
}

// MFMA helper: 16 rank-updates of the 4x4 fragment grid
static __device__ __forceinline__ void mm16(const bf16x8 (&a)[4], const bf16x8 (&b)[4],
                                            f32x4 (&acc)[4][4]) {
#pragma unroll
    for (int r = 0; r < 4; ++r)
#pragma unroll
        for (int t = 0; t < 4; ++t)
            acc[r][t] = __builtin_amdgcn_mfma_f32_16x16x32_bf16(a[r], b[t], acc[r][t], 0, 0, 0);
}

// ---------------- kernel 3: fused score GEMM + tanh + Wm dot ----------------
// 512 threads (8 waves); one 64-row panel per block; full K=1024 in LDS.
// B from packed layout (1KB coalesced wave loads); A ds_reads prefetched 2 k-steps
// ahead, B 2-3 ahead, explicit named buffers (no runtime-indexed arrays).
__global__ __launch_bounds__(512, 2) void fused_score_kernel(
    const float* __restrict__ value, const float* __restrict__ cov,
    const short* __restrict__ wv_pk, const float* __restrict__ qh,
    const float* __restrict__ Wc, const float* __restrict__ Wm,
    float* __restrict__ e_out)
{
    extern __shared__ char smem[];
    float* e_sm = (float*)(smem + 64 * 1024 * 2);

    const int p   = blockIdx.x;
    const int b   = p >> 5;
    const int n0  = (p & 31) * 64;
    const int tid = threadIdx.x;

    if (tid < 64) e_sm[tid] = 0.f;

    // ---- stage value[b, n0..n0+64, :] as bf16 into swizzled LDS ----
    const float* src = value + ((size_t)(b * N_SZ + n0)) * H_SZ;
#pragma unroll 4
    for (int it = 0; it < 32; ++it) {
        int idx = (it * 512 + tid) * 4;
        float4 v = *(const float4*)(src + idx);
        int row = idx >> 10;
        int col = idx & 1023;
        unsigned byteoff = (unsigned)(row * 2048 + col * 2) ^ (unsigned)((row & 7) << 4);
        short4 s;
        s.x = (short)f2bf(v.x); s.y = (short)f2bf(v.y);
        s.z = (short)f2bf(v.z); s.w = (short)f2bf(v.w);
        *(short4*)(smem + byteoff) = s;
    }
    __syncthreads();

    const int wave = tid >> 6;
    const int lane = tid & 63;
    const int lrow = lane & 15;
    const int lgrp = lane >> 4;
    const unsigned xorm = (unsigned)((lrow & 7) << 4);
    // 4 swizzled bases (k-parity x r-high): every ds offset folds to +immediate
    const unsigned be0 = ((unsigned)(lrow * 2048 + lgrp * 16)) ^ xorm;          // k even, r<2
    const unsigned bo0 = ((unsigned)(lrow * 2048 + 64 + lgrp * 16)) ^ xorm;     // k odd,  r<2
    const unsigned be1 = be0 + 65536;                                           // k even, r>=2
    const unsigned bo1 = bo0 + 65536;                                           // k odd,  r>=2

// A-fragment ds loads for k-unit kk (parity must match base pair)
#define LDA(dst, kk, P0, P1)                                                    \
    dst[0] = *(const bf16x8*)(smem + P0 + (unsigned)(((kk) >> 1) * 128));       \
    dst[1] = *(const bf16x8*)(smem + P0 + 32768u + (unsigned)(((kk) >> 1) * 128)); \
    dst[2] = *(const bf16x8*)(smem + P1 + (unsigned)(((kk) >> 1) * 128));       \
    dst[3] = *(const bf16x8*)(smem + P1 + 32768u + (unsigned)(((kk) >> 1) * 128));
// B-fragment loads (contiguous 1KB per wave instruction)
#define LDB(dst, kk)                                                            \
    dst[0] = *(const bf16x8*)(bbase + (kk) * 2048);                             \
    dst[1] = *(const bf16x8*)(bbase + (kk) * 2048 + 512);                       \
    dst[2] = *(const bf16x8*)(bbase + (kk) * 2048 + 1024);                      \
    dst[3] = *(const bf16x8*)(bbase + (kk) * 2048 + 1536);

    float cv[4][4];
#pragma unroll
    for (int r = 0; r < 4; ++r)
#pragma unroll
        for (int i = 0; i < 4; ++i)
            cv[r][i] = cov[b * N_SZ + n0 + 16 * r + lgrp * 4 + i];

    float s_part[4][4];
#pragma unroll
    for (int r = 0; r < 4; ++r)
#pragma unroll
        for (int i = 0; i < 4; ++i) s_part[r][i] = 0.f;

#pragma unroll 1
    for (int j = 0; j < 2; ++j) {
        const int gbase = wave * 128 + j * 64;
        const int wslot = wave * 2 + j;              // 64-g block index, 0..15
        const short* bbase = wv_pk + (size_t)wslot * 65536 + lane * 8;

        f32x4 acc[4][4];
#pragma unroll
        for (int r = 0; r < 4; ++r)
#pragma unroll
            for (int t = 0; t < 4; ++t) acc[r][t] = (f32x4){0.f, 0.f, 0.f, 0.f};

        // pipeline prologue: A and B for k=0,1 in flight
        bf16x8 aA[4], aB[4], bA[4], bB[4];
        LDB(bA, 0)
        LDB(bB, 1)
        LDA(aA, 0, be0, be1)
        LDA(aB, 1, bo0, bo1)

#pragma unroll 2
        for (int k = 0; k < 32; k += 2) {
            bf16x8 aN[4], aM[4], bN[4], bM[4];
            // prefetch k+2 / k+3 (B first: longest latency). Wrap harmlessly.
            LDB(bN, ((k + 2) & 31))
            LDB(bM, ((k + 3) & 31))
            LDA(aN, ((k + 2) & 31), be0, be1)
            LDA(aM, ((k + 3) & 31), bo0, bo1)
            mm16(aA, bA, acc);
            mm16(aB, bB, acc);
#pragma unroll
            for (int t = 0; t < 4; ++t) {
                aA[t] = aN[t]; aB[t] = aM[t];
                bA[t] = bN[t]; bB[t] = bM[t];
            }
        }

        // epilogue: a = acc + qh + cov*Wc ; e_part += tanh(a)*Wm
#pragma unroll
        for (int t = 0; t < 4; ++t) {
            int g = gbase + 16 * t + lrow;
            float qv = qh[b * 1024 + g];
            float wc = Wc[g];
            float wm = Wm[g];
#pragma unroll
            for (int r = 0; r < 4; ++r)
#pragma unroll
                for (int i = 0; i < 4; ++i) {
                    float aval = acc[r][t][i] + qv + cv[r][i] * wc;
                    s_part[r][i] += fast_tanh(aval) * wm;
                }
        }
    }
#undef LDA
#undef LDB

    // reduce across the 16 lanes sharing a row, then accumulate into LDS
#pragma unroll
    for (int r = 0; r < 4; ++r)
#pragma unroll
        for (int i = 0; i < 4; ++i) {
            float s = s_part[r][i];
            s += __shfl_xor(s, 1);
            s += __shfl_xor(s, 2);
            s += __shfl_xor(s, 4);
            s += __shfl_xor(s, 8);
            if (lrow == 0) atomicAdd(&e_sm[16 * r + lgrp * 4 + i], s);
        }
    __syncthreads();
    if (tid < 64) e_out[b * N_SZ + n0 + tid] = e_sm[tid];
}

// ---------------- kernel 4: mask + softmax over n ----------------
__global__ __launch_bounds__(256) void softmax_kernel(const float* __restrict__ e,
                                                      const int* __restrict__ mask,
                                                      const float* __restrict__ bm,
                                                      float* __restrict__ attn_out) {
    int b = blockIdx.x;
    int t = threadIdx.x;
    int wave = t >> 6, lane = t & 63;
    float bmv = bm[0];
    float vals[8];
    float mx = -1e30f;
#pragma unroll
    for (int j = 0; j < 8; ++j) {
        int n = t + 256 * j;
        float ev = e[b * N_SZ + n] + bmv;
        if (mask[b * N_SZ + n] <= 0) ev = -1e9f;
        vals[j] = ev;
        mx = fmaxf(mx, ev);
    }
#pragma unroll
    for (int m = 1; m < 64; m <<= 1) mx = fmaxf(mx, __shfl_xor(mx, m));
    __shared__ float redmax[4], redsum[4];
    if (lane == 0) redmax[wave] = mx;
    __syncthreads();
    mx = fmaxf(fmaxf(redmax[0], redmax[1]), fmaxf(redmax[2], redmax[3]));
    float sum = 0.f;
#pragma unroll
    for (int j = 0; j < 8; ++j) {
        vals[j] = expf(vals[j] - mx);
        sum += vals[j];
    }
#pragma unroll
    for (int m = 1; m < 64; m <<= 1) sum += __shfl_xor(sum, m);
    if (lane == 0) redsum[wave] = sum;
    __syncthreads();
    sum = redsum[0] + redsum[1] + redsum[2] + redsum[3];
    float inv = 1.f / sum;
#pragma unroll
    for (int j = 0; j < 8; ++j)
        attn_out[b * N_SZ + t + 256 * j] = vals[j] * inv;
}

// ---------------- kernel 5: partial weighted value sum (16 chunks/batch) ----------------
__global__ __launch_bounds__(256) void wsum_partial_kernel(const float* __restrict__ attn,
                                                           const float* __restrict__ value,
                                                           float* __restrict__ partial) {
    int b = blockIdx.x >> 4;
    int c = blockIdx.x & 15;
    int t = threadIdx.x;
    float4 acc = {0.f, 0.f, 0.f, 0.f};
    const float* vbase = value + (size_t)(b * N_SZ + c * 128) * H_SZ;
    const float* abase = attn + b * N_SZ + c * 128;
    for (int n = 0; n < 128; ++n) {
        float a = abase[n];
        if (a != 0.f) {
            float4 v = *(const float4*)(vbase + (size_t)n * H_SZ + t * 4);
            acc.x += a * v.x; acc.y += a * v.y;
            acc.z += a * v.z; acc.w += a * v.w;
        }
    }
    *(float4*)(partial + (size_t)blockIdx.x * H_SZ + t * 4) = acc;
}

// ---------------- kernel 6: reduce partials -> output ----------------
__global__ __launch_bounds__(256) void wsum_reduce_kernel(const float* __restrict__ partial,
                                                          float* __restrict__ out) {
    int i = blockIdx.x * 256 + threadIdx.x;   // 32768 total
    int b = i >> 10;
    int h = i & 1023;
    float s = 0.f;
#pragma unroll
    for (int c = 0; c < 16; ++c) s += partial[(size_t)(b * 16 + c) * H_SZ + h];
    out[i] = s;
}

extern "C" void kernel_launch(void* const* d_in, const int* in_sizes, int n_in,
                              void* d_out, int out_size, void* d_ws, size_t ws_size,
                              hipStream_t stream) {
    const float* query = (const float*)d_in[0];
    const float* value = (const float*)d_in[1];
    const int*   mask  = (const int*)  d_in[2];
    const float* cov   = (const float*)d_in[3];
    const float* Wq    = (const float*)d_in[4];
    const float* Wv    = (const float*)d_in[5];
    const float* Wc    = (const float*)d_in[6];
    const float* bias  = (const float*)d_in[7];
    const float* Wm    = (const float*)d_in[8];
    const float* bm    = (const float*)d_in[9];

    float* out      = (float*)d_out;            // [32*1024] output
    float* attn_out = out + B_SZ * H_SZ;        // [32*2048] attn

    char* ws = (char*)d_ws;
    short* wv_pk   = (short*)ws;                                       // 2 MB
    float* qh      = (float*)(ws + 2 * 1024 * 1024);                   // 128 KB
    float* e_buf   = (float*)(ws + 2 * 1024 * 1024 + 128 * 1024);      // 256 KB
    float* partial = (float*)(ws + 2 * 1024 * 1024 + 384 * 1024);      // 2 MB

    pack_wv_kernel<<<512, 256, 0, stream>>>(Wv, wv_pk);
    qhid_kernel<<<256, 256, 0, stream>>>(query, Wq, bias, qh);

    size_t smem = 64 * 1024 * 2 + 64 * 4;
    fused_score_kernel<<<1024, 512, smem, stream>>>(value, cov, wv_pk, qh, Wc, Wm, e_buf);

    softmax_kernel<<<B_SZ, 256, 0, stream>>>(e_buf, mask, bm, attn_out);
    wsum_partial_kernel<<<B_SZ * 16, 256, 0, stream>>>(attn_out, value, partial);
    wsum_reduce_kernel<<<128, 256, 0, stream>>>(partial, out);
}

// Round 6
// 230.918 us; speedup vs baseline: 3.3648x; 1.0504x over previous
//
#include <hip/hip_runtime.h>
#include <hip/hip_bf16.h>

#define B_SZ 32
#define N_SZ 2048
#define H_SZ 1024

typedef float f32x4 __attribute__((ext_vector_type(4)));
typedef short bf16x8 __attribute__((ext_vector_type(8)));

static __device__ __forceinline__ unsigned short f2bf(float f) {
    union { float f; unsigned u; } x; x.f = f;
    unsigned r = x.u + 0x7FFF + ((x.u >> 16) & 1);
    return (unsigned short)(r >> 16);
}

// fast tanh: (e^{2x}-1)/(e^{2x}+1), clamped so e never overflows
static __device__ __forceinline__ float fast_tanh(float x) {
    x = fminf(fmaxf(x, -15.f), 15.f);
    float e = __expf(2.f * x);
    return (e - 1.f) / (e + 1.f);
}

// ---------------- kernel 1: pack Wv f32 -> bf16 in wave-fragment order ----------------
// packed element index: ((((w*32 + k)*4 + t)*64) + lane)*8 + j
//   maps to Wv[g][h], g = w*64 + 16t + (lane&15), h = k*32 + (lane>>4)*8 + j
__global__ __launch_bounds__(256) void pack_wv_kernel(const float* __restrict__ wv,
                                                      short* __restrict__ out) {
    int o8 = blockIdx.x * 256 + threadIdx.x;      // 131072 threads, 8 elems each
    int lane = o8 & 63;
    int t    = (o8 >> 6) & 3;
    int k    = (o8 >> 8) & 31;
    int w    = (o8 >> 13) & 15;
    int g  = w * 64 + 16 * t + (lane & 15);
    int h0 = k * 32 + (lane >> 4) * 8;
    const float* src = wv + (size_t)g * 1024 + h0;
    float4 v0 = *(const float4*)(src);
    float4 v1 = *(const float4*)(src + 4);
    short4 s0, s1;
    s0.x = (short)f2bf(v0.x); s0.y = (short)f2bf(v0.y);
    s0.z = (short)f2bf(v0.z); s0.w = (short)f2bf(v0.w);
    s1.x = (short)f2bf(v1.x); s1.y = (short)f2bf(v1.y);
    s1.z = (short)f2bf(v1.z); s1.w = (short)f2bf(v1.w);
    *(short4*)(out + (size_t)o8 * 8)     = s0;
    *(short4*)(out + (size_t)o8 * 8 + 4) = s1;
}

// ---------------- kernel 2: q_hid = query @ Wq.T + bias ----------------
__global__ __launch_bounds__(256) void qhid_kernel(const float* __restrict__ query,
                                                   const float* __restrict__ Wq,
                                                   const float* __restrict__ bias,
                                                   float* __restrict__ qh) {
    int gb = blockIdx.x * 4;
    __shared__ float wsm[4][1024];
    int t = threadIdx.x;
    for (int i = t; i < 4096; i += 256)
        wsm[i >> 10][i & 1023] = Wq[(size_t)gb * 1024 + i];
    __syncthreads();
    int gi = t >> 6;
    int lane = t & 63;
    int b = lane >> 1;
    int half = lane & 1;
    const float4* q = (const float4*)(query + b * 1024 + half * 512);
    const float4* w = (const float4*)(&wsm[gi][half * 512]);
    float acc = 0.f;
#pragma unroll 8
    for (int h = 0; h < 128; ++h) {
        float4 qv = q[h]; float4 wv = w[h];
        acc += qv.x * wv.x + qv.y * wv.y + qv.z * wv.z + qv.w * wv.w;
    }
    acc += __shfl_xor(acc, 1);
    if (half == 0) qh[b * 1024 + gb + gi] = acc + bias[gb + gi];
}

// ---------------- kernel 3: fused score GEMM + tanh + Wm dot ----------------
// 1024 threads (16 waves, 4 waves/SIMD); one 64-row panel per block; full K=1024
// in LDS (stage once). Each wave owns one 64-g slice (wslot = wave). Depth-1
// ping/pong B prefetch from the packed layout (1KB coalesced wave loads).
__global__ __launch_bounds__(1024, 4) void fused_score_kernel(
    const float* __restrict__ value, const float* __restrict__ cov,
    const short* __restrict__ wv_pk, const float* __restrict__ qh,
    const float* __restrict__ Wc, const float* __restrict__ Wm,
    float* __restrict__ e_out)
{
    extern __shared__ char smem[];
    float* e_sm = (float*)(smem + 64 * 1024 * 2);

    const int p   = blockIdx.x;
    const int b   = p >> 5;
    const int n0  = (p & 31) * 64;
    const int tid = threadIdx.x;

    if (tid < 64) e_sm[tid] = 0.f;

    // ---- stage value[b, n0..n0+64, :] as bf16 into swizzled LDS ----
    const float* src = value + ((size_t)(b * N_SZ + n0)) * H_SZ;
#pragma unroll 4
    for (int it = 0; it < 16; ++it) {
        int idx = (it * 1024 + tid) * 4;
        float4 v = *(const float4*)(src + idx);
        int row = idx >> 10;
        int col = idx & 1023;
        unsigned byteoff = (unsigned)(row * 2048 + col * 2) ^ (unsigned)((row & 7) << 4);
        short4 s;
        s.x = (short)f2bf(v.x); s.y = (short)f2bf(v.y);
        s.z = (short)f2bf(v.z); s.w = (short)f2bf(v.w);
        *(short4*)(smem + byteoff) = s;
    }
    __syncthreads();

    const int wave = tid >> 6;
    const int lane = tid & 63;
    const int lrow = lane & 15;
    const int lgrp = lane >> 4;
    const unsigned xorm = (unsigned)((lrow & 7) << 4);
    // carry-safe swizzled bases: all k/r offsets fold to +immediate
    const unsigned base_e = ((unsigned)(lrow * 2048 + lgrp * 16)) ^ xorm;      // k even
    const unsigned base_o = ((unsigned)(lrow * 2048 + 64 + lgrp * 16)) ^ xorm; // k odd

    float cv[4][4];
#pragma unroll
    for (int r = 0; r < 4; ++r)
#pragma unroll
        for (int i = 0; i < 4; ++i)
            cv[r][i] = cov[b * N_SZ + n0 + 16 * r + lgrp * 4 + i];

    const int gbase = wave * 64;                 // this wave's 64-g slice
    const short* bbase = wv_pk + (size_t)wave * 65536 + lane * 8;

    f32x4 acc[4][4];
#pragma unroll
    for (int r = 0; r < 4; ++r)
#pragma unroll
        for (int t = 0; t < 4; ++t) acc[r][t] = (f32x4){0.f, 0.f, 0.f, 0.f};

    // depth-1 ping/pong prefetch for B fragments (coalesced 1KB loads)
    bf16x8 bc[4];
#pragma unroll
    for (int t = 0; t < 4; ++t)
        bc[t] = *(const bf16x8*)(bbase + t * 512);

#pragma unroll 2
    for (int k = 0; k < 32; ++k) {
        // issue next-k B loads first (wrap at end: harmless re-load of k=0)
        bf16x8 bn[4];
        int kn = (k + 1) & 31;
#pragma unroll
        for (int t = 0; t < 4; ++t)
            bn[t] = *(const bf16x8*)(bbase + kn * 2048 + t * 512);

        bf16x8 afr[4];
#pragma unroll
        for (int r = 0; r < 4; ++r) {
            unsigned off = ((k & 1) ? base_o : base_e) + (unsigned)(r * 32768 + (k >> 1) * 128);
            afr[r] = *(const bf16x8*)(smem + off);
        }
#pragma unroll
        for (int r = 0; r < 4; ++r)
#pragma unroll
            for (int t = 0; t < 4; ++t)
                acc[r][t] = __builtin_amdgcn_mfma_f32_16x16x32_bf16(
                    afr[r], bc[t], acc[r][t], 0, 0, 0);
#pragma unroll
        for (int t = 0; t < 4; ++t) bc[t] = bn[t];
    }

    // epilogue: a = acc + qh + cov*Wc ; e_part += tanh(a)*Wm
    float s_part[4][4];
#pragma unroll
    for (int r = 0; r < 4; ++r)
#pragma unroll
        for (int i = 0; i < 4; ++i) s_part[r][i] = 0.f;

#pragma unroll
    for (int t = 0; t < 4; ++t) {
        int g = gbase + 16 * t + lrow;
        float qv = qh[b * 1024 + g];
        float wc = Wc[g];
        float wm = Wm[g];
#pragma unroll
        for (int r = 0; r < 4; ++r)
#pragma unroll
            for (int i = 0; i < 4; ++i) {
                float aval = acc[r][t][i] + qv + cv[r][i] * wc;
                s_part[r][i] += fast_tanh(aval) * wm;
            }
    }

    // reduce across the 16 lanes sharing a row, then accumulate into LDS
#pragma unroll
    for (int r = 0; r < 4; ++r)
#pragma unroll
        for (int i = 0; i < 4; ++i) {
            float s = s_part[r][i];
            s += __shfl_xor(s, 1);
            s += __shfl_xor(s, 2);
            s += __shfl_xor(s, 4);
            s += __shfl_xor(s, 8);
            if (lrow == 0) atomicAdd(&e_sm[16 * r + lgrp * 4 + i], s);
        }
    __syncthreads();
    if (tid < 64) e_out[b * N_SZ + n0 + tid] = e_sm[tid];
}

// ---------------- kernel 4: mask + softmax over n ----------------
__global__ __launch_bounds__(256) void softmax_kernel(const float* __restrict__ e,
                                                      const int* __restrict__ mask,
                                                      const float* __restrict__ bm,
                                                      float* __restrict__ attn_out) {
    int b = blockIdx.x;
    int t = threadIdx.x;
    int wave = t >> 6, lane = t & 63;
    float bmv = bm[0];
    float vals[8];
    float mx = -1e30f;
#pragma unroll
    for (int j = 0; j < 8; ++j) {
        int n = t + 256 * j;
        float ev = e[b * N_SZ + n] + bmv;
        if (mask[b * N_SZ + n] <= 0) ev = -1e9f;
        vals[j] = ev;
        mx = fmaxf(mx, ev);
    }
#pragma unroll
    for (int m = 1; m < 64; m <<= 1) mx = fmaxf(mx, __shfl_xor(mx, m));
    __shared__ float redmax[4], redsum[4];
    if (lane == 0) redmax[wave] = mx;
    __syncthreads();
    mx = fmaxf(fmaxf(redmax[0], redmax[1]), fmaxf(redmax[2], redmax[3]));
    float sum = 0.f;
#pragma unroll
    for (int j = 0; j < 8; ++j) {
        vals[j] = expf(vals[j] - mx);
        sum += vals[j];
    }
#pragma unroll
    for (int m = 1; m < 64; m <<= 1) sum += __shfl_xor(sum, m);
    if (lane == 0) redsum[wave] = sum;
    __syncthreads();
    sum = redsum[0] + redsum[1] + redsum[2] + redsum[3];
    float inv = 1.f / sum;
#pragma unroll
    for (int j = 0; j < 8; ++j)
        attn_out[b * N_SZ + t + 256 * j] = vals[j] * inv;
}

// ---------------- kernel 5: partial weighted value sum (16 chunks/batch) ----------------
__global__ __launch_bounds__(256) void wsum_partial_kernel(const float* __restrict__ attn,
                                                           const float* __restrict__ value,
                                                           float* __restrict__ partial) {
    int b = blockIdx.x >> 4;
    int c = blockIdx.x & 15;
    int t = threadIdx.x;
    float4 acc = {0.f, 0.f, 0.f, 0.f};
    const float* vbase = value + (size_t)(b * N_SZ + c * 128) * H_SZ;
    const float* abase = attn + b * N_SZ + c * 128;
    for (int n = 0; n < 128; ++n) {
        float a = abase[n];
        if (a != 0.f) {
            float4 v = *(const float4*)(vbase + (size_t)n * H_SZ + t * 4);
            acc.x += a * v.x; acc.y += a * v.y;
            acc.z += a * v.z; acc.w += a * v.w;
        }
    }
    *(float4*)(partial + (size_t)blockIdx.x * H_SZ + t * 4) = acc;
}

// ---------------- kernel 6: reduce partials -> output ----------------
__global__ __launch_bounds__(256) void wsum_reduce_kernel(const float* __restrict__ partial,
                                                          float* __restrict__ out) {
    int i = blockIdx.x * 256 + threadIdx.x;   // 32768 total
    int b = i >> 10;
    int h = i & 1023;
    float s = 0.f;
#pragma unroll
    for (int c = 0; c < 16; ++c) s += partial[(size_t)(b * 16 + c) * H_SZ + h];
    out[i] = s;
}

extern "C" void kernel_launch(void* const* d_in, const int* in_sizes, int n_in,
                              void* d_out, int out_size, void* d_ws, size_t ws_size,
                              hipStream_t stream) {
    const float* query = (const float*)d_in[0];
    const float* value = (const float*)d_in[1];
    const int*   mask  = (const int*)  d_in[2];
    const float* cov   = (const float*)d_in[3];
    const float* Wq    = (const float*)d_in[4];
    const float* Wv    = (const float*)d_in[5];
    const float* Wc    = (const float*)d_in[6];
    const float* bias  = (const float*)d_in[7];
    const float* Wm    = (const float*)d_in[8];
    const float* bm    = (const float*)d_in[9];

    float* out      = (float*)d_out;            // [32*1024] output
    float* attn_out = out + B_SZ * H_SZ;        // [32*2048] attn

    char* ws = (char*)d_ws;
    short* wv_pk   = (short*)ws;                                       // 2 MB
    float* qh      = (float*)(ws + 2 * 1024 * 1024);                   // 128 KB
    float* e_buf   = (float*)(ws + 2 * 1024 * 1024 + 128 * 1024);      // 256 KB
    float* partial = (float*)(ws + 2 * 1024 * 1024 + 384 * 1024);      // 2 MB

    pack_wv_kernel<<<512, 256, 0, stream>>>(Wv, wv_pk);
    qhid_kernel<<<256, 256, 0, stream>>>(query, Wq, bias, qh);

    size_t smem = 64 * 1024 * 2 + 64 * 4;
    fused_score_kernel<<<1024, 1024, smem, stream>>>(value, cov, wv_pk, qh, Wc, Wm, e_buf);

    softmax_kernel<<<B_SZ, 256, 0, stream>>>(e_buf, mask, bm, attn_out);
    wsum_partial_kernel<<<B_SZ * 16, 256, 0, stream>>>(attn_out, value, partial);
    wsum_reduce_kernel<<<128, 256, 0, stream>>>(partial, out);
}